// Round 2
// baseline (6170.811 us; speedup 1.0000x reference)
//
#include <hip/hip_runtime.h>

// ---------------- problem constants ----------------
#define VV 50000
#define EE 512
#define HH 256
#define BB 32
#define SS 1024
#define G4 1024   // 4*H

typedef __attribute__((ext_vector_type(8))) short short8;
typedef __attribute__((ext_vector_type(4))) float float4v;
typedef __attribute__((ext_vector_type(2))) float float2v;
typedef __attribute__((ext_vector_type(4))) unsigned short ushort4v;

#define MFMA(a, b, c) __builtin_amdgcn_mfma_f32_16x16x32_bf16(a, b, c, 0, 0, 0)

__device__ __forceinline__ float b2f(unsigned short u) {
  union { unsigned int i; float f; } v; v.i = ((unsigned int)u) << 16; return v.f;
}
__device__ __forceinline__ unsigned short f2b(float f) {
  union { float f; unsigned int i; } v; v.f = f;
  unsigned int u = v.i;
  return (unsigned short)((u + 0x7fffu + ((u >> 16) & 1u)) >> 16);
}
// pack 8 consecutive fp32 (16B-aligned) -> short8 of bf16
__device__ __forceinline__ short8 pack8(const float* p) {
  float4v x0 = *(const float4v*)p;
  float4v x1 = *(const float4v*)(p + 4);
  short8 r;
  r[0] = (short)f2b(x0[0]); r[1] = (short)f2b(x0[1]);
  r[2] = (short)f2b(x0[2]); r[3] = (short)f2b(x0[3]);
  r[4] = (short)f2b(x1[0]); r[5] = (short)f2b(x1[1]);
  r[6] = (short)f2b(x1[2]); r[7] = (short)f2b(x1[3]);
  return r;
}
__device__ __forceinline__ float sigm(float x) {
  return __builtin_amdgcn_rcpf(1.0f + __expf(-x));
}
__device__ __forceinline__ float tanh_f(float x) {
  return 1.0f - 2.0f * __builtin_amdgcn_rcpf(__expf(2.0f * x) + 1.0f);
}

// ---------------- kernel 1: fmask scan -> order/counts ----------------
__global__ __launch_bounds__(256) void k_scan(const int* __restrict__ fmask,
                                              int* __restrict__ order,
                                              int* __restrict__ counts) {
  __shared__ int sh[256];
  const int b = blockIdx.x;
  const int tid = threadIdx.x;
  int m0[4];
  const int base = b * SS + tid * 4;
#pragma unroll
  for (int j = 0; j < 4; ++j) m0[j] = fmask[base + j];
  const int s = m0[0] + m0[1] + m0[2] + m0[3];
  sh[tid] = s;
  __syncthreads();
  for (int off = 1; off < 256; off <<= 1) {
    int v = 0;
    if (tid >= off) v = sh[tid - off];
    __syncthreads();
    sh[tid] += v;
    __syncthreads();
  }
  const int incl = sh[tid];
  int pos = incl - s;
#pragma unroll
  for (int j = 0; j < 4; ++j) {
    if (m0[j]) order[b * SS + pos++] = tid * 4 + j;
  }
  if (tid == 255) counts[b] = incl;
}

// ---------------- kernel 2: embedding-gather + input GEMM ----------------
// xg[d][t][g][b] (bf16) = sum_k emb[tok(d,b,t)][k] * Wih_d[g][k] + bih_d[g] + bhh_d[g]
// emb/Wih are fp32 in HBM; converted to bf16 while staging to LDS.
#define BM 128
#define BN 128
#define BK 32
#define LSTR 56   // padded LDS row stride (elements): 112B, 16B-aligned

__global__ __launch_bounds__(256, 2) void k_gemm(
    const int* __restrict__ inputs, const int* __restrict__ seqlen,
    const float* __restrict__ emb,
    const float* __restrict__ Wih_f, const float* __restrict__ Wih_b,
    const float* __restrict__ bih_f, const float* __restrict__ bih_b,
    const float* __restrict__ bhh_f, const float* __restrict__ bhh_b,
    unsigned short* __restrict__ xg) {
  __shared__ short As[BM * LSTR];
  __shared__ short Bs[BN * LSTR];
  __shared__ int tokL[BM];

  const int d = blockIdx.y;
  const int mt = blockIdx.x >> 3, nt = blockIdx.x & 7;
  const int Mbase = mt * BM, Nbase = nt * BN;
  const int tid = threadIdx.x;
  const float* Wih = d ? Wih_b : Wih_f;

  if (tid < BM) {
    const int m = Mbase + tid;
    const int t = m >> 5, b = m & 31;
    int tok;
    if (d == 0) {
      tok = inputs[b * SS + t];
    } else {
      const int L = seqlen[b];
      tok = (t < L) ? inputs[b * SS + (L - 1 - t)] : 0;
    }
    tokL[tid] = tok;
  }
  __syncthreads();

  const int wave = tid >> 6, lane = tid & 63, ln = lane & 15, q = lane >> 4;
  const int wm = wave & 1, wn = wave >> 1;

  float4v acc[4][4];
#pragma unroll
  for (int mi = 0; mi < 4; ++mi)
#pragma unroll
    for (int ni = 0; ni < 4; ++ni) acc[mi][ni] = (float4v){0.f, 0.f, 0.f, 0.f};

  for (int kb = 0; kb < (EE / BK); ++kb) {
    const int k0 = kb * BK;
    if (kb) __syncthreads();
#pragma unroll
    for (int i = 0; i < 2; ++i) {
      const int c = tid + i * 256;       // 512 chunks of 8 elems per tile
      const int row = c >> 2, sub = c & 3;
      const short8 av = pack8(emb + (size_t)tokL[row] * EE + k0 + sub * 8);
      *(short8*)(As + row * LSTR + sub * 8) = av;
      const short8 bv = pack8(Wih + (size_t)(Nbase + row) * EE + k0 + sub * 8);
      *(short8*)(Bs + row * LSTR + sub * 8) = bv;
    }
    __syncthreads();
    short8 af[4], bfr[4];
#pragma unroll
    for (int mi = 0; mi < 4; ++mi)
      af[mi] = *(const short8*)(As + (wm * 64 + mi * 16 + ln) * LSTR + q * 8);
#pragma unroll
    for (int ni = 0; ni < 4; ++ni)
      bfr[ni] = *(const short8*)(Bs + (wn * 64 + ni * 16 + ln) * LSTR + q * 8);
#pragma unroll
    for (int mi = 0; mi < 4; ++mi)
#pragma unroll
      for (int ni = 0; ni < 4; ++ni)
        acc[mi][ni] = MFMA(af[mi], bfr[ni], acc[mi][ni]);
  }

  const float* bih = d ? bih_b : bih_f;
  const float* bhh = d ? bhh_b : bhh_f;
  float biasv[4];
#pragma unroll
  for (int ni = 0; ni < 4; ++ni) {
    const int col = Nbase + wn * 64 + ni * 16 + ln;
    biasv[ni] = bih[col] + bhh[col];
  }
#pragma unroll
  for (int mi = 0; mi < 4; ++mi) {
    const int mrow = Mbase + wm * 64 + mi * 16 + q * 4;
    const int t = mrow >> 5, b0 = mrow & 31;
#pragma unroll
    for (int ni = 0; ni < 4; ++ni) {
      const int gcol = Nbase + wn * 64 + ni * 16 + ln;
      ushort4v pk;
#pragma unroll
      for (int r = 0; r < 4; ++r) pk[r] = f2b(acc[mi][ni][r] + biasv[ni]);
      *(ushort4v*)(xg + (((size_t)d * SS + t) * G4 + gcol) * BB + b0) = pk;
    }
  }
}

// ---------------- kernel 3: recurrence ----------------
// 16 active workgroups: (dir d in {0,1}) x (unit-slice k in [0,8)).
// Each wg: all 32 chains, units [32k,32k+32). W_hh slice lives in VGPRs (bf16).
// Per-direction arrival counter (monotonic) synchronizes the 8 slices per step.
__global__ __launch_bounds__(256, 1) void k_recur(
    const float* __restrict__ Whh_f, const float* __restrict__ Whh_b,
    const unsigned short* __restrict__ xg, unsigned short* __restrict__ hbuf,
    int* __restrict__ ctr) {
  const int beta = blockIdx.x;
  const int xcd = beta & 7, slot = beta >> 3;   // blockIdx%8 ~ XCD (perf heuristic only)
  if (xcd >= 2) return;
  const int d = xcd, k = slot;
  const float* Whh = d ? Whh_b : Whh_f;
  const int tid = threadIdx.x;
  const int wave = tid >> 6, lane = tid & 63, ln = lane & 15, q = lane >> 4;
  const int g = wave & 1, nw = wave >> 1;
  const int chain = nw * 16 + ln;               // this lane's batch chain (C col)
  const int ubase = k * 32 + g * 16 + q * 4;    // first of this lane's 4 units (C rows)

  // loop-invariant weight fragments: A[m][kk], m=ln (unit-within-16), kk=q*8+j
  short8 w[4][8];
#pragma unroll
  for (int G = 0; G < 4; ++G) {
    const int grow = G * 256 + k * 32 + g * 16 + ln;
#pragma unroll
    for (int kt = 0; kt < 8; ++kt)
      w[G][kt] = pack8(Whh + (size_t)grow * HH + kt * 32 + q * 8);
  }

  float c4[4] = {0.f, 0.f, 0.f, 0.f};
  unsigned short* hb = hbuf + (size_t)d * 1025 * BB * HH;
  const unsigned short* xgd = xg + (size_t)d * SS * G4 * BB;
  int* myctr = ctr + d;

  for (int t = 0; t < SS; ++t) {
    // prefetch xg (independent of sync -> latency hidden under spin)
    unsigned short xgu[4][4];
#pragma unroll
    for (int G = 0; G < 4; ++G)
#pragma unroll
      for (int r = 0; r < 4; ++r)
        xgu[G][r] = xgd[((size_t)t * G4 + (G * 256 + ubase + r)) * BB + chain];

    if (t > 0) {
      const int target = 8 * t;
      while (__hip_atomic_load(myctr, __ATOMIC_ACQUIRE, __HIP_MEMORY_SCOPE_AGENT) < target)
        __builtin_amdgcn_s_sleep(2);
    }

    // B fragments: h_{t-1}[chain][k] rows, contiguous 16B
    const unsigned short* hrow = hb + ((size_t)t * BB + chain) * HH;
    short8 hf[8];
#pragma unroll
    for (int kt = 0; kt < 8; ++kt)
      hf[kt] = *(const short8*)(hrow + kt * 32 + q * 8);

    float4v acc[4];
#pragma unroll
    for (int G = 0; G < 4; ++G) acc[G] = (float4v){0.f, 0.f, 0.f, 0.f};
#pragma unroll
    for (int kt = 0; kt < 8; ++kt)
#pragma unroll
      for (int G = 0; G < 4; ++G)
        acc[G] = MFMA(w[G][kt], hf[kt], acc[G]);

    unsigned long long pv = 0ull;
#pragma unroll
    for (int r = 0; r < 4; ++r) {
      const float gi = acc[0][r] + b2f(xgu[0][r]);
      const float gf = acc[1][r] + b2f(xgu[1][r]);
      const float gg = acc[2][r] + b2f(xgu[2][r]);
      const float go = acc[3][r] + b2f(xgu[3][r]);
      const float cn = sigm(gf) * c4[r] + sigm(gi) * tanh_f(gg);
      c4[r] = cn;
      const float h = sigm(go) * tanh_f(cn);
      pv |= ((unsigned long long)f2b(h)) << (16 * r);
    }
    // 4 consecutive units of one chain -> single coherent 8B store
    __hip_atomic_store((unsigned long long*)(hb + ((size_t)(t + 1) * BB + chain) * HH + ubase),
                       pv, __ATOMIC_RELAXED, __HIP_MEMORY_SCOPE_AGENT);
    __syncthreads();
    if (tid == 0)
      __hip_atomic_fetch_add(myctr, 1, __ATOMIC_RELEASE, __HIP_MEMORY_SCOPE_AGENT);
  }
}

// ---------------- kernel 4: masked compaction gather -> out (fp32) ----------------
__global__ __launch_bounds__(256) void k_gather(
    const unsigned short* __restrict__ hbuf, const int* __restrict__ order,
    const int* __restrict__ counts, float* __restrict__ out) {
  const int bj = blockIdx.x;            // (b, j)
  const int b = bj >> 10, j = bj & 1023;
  const int tid = threadIdx.x;
  const int cnt = counts[b];
  float2v val = (float2v){0.f, 0.f};
  if (j < cnt) {
    const int half = tid >> 7;          // 0: forward, 1: backward
    const int e2 = (tid & 127) * 2;
    const int tsel = half ? order[b * SS + (cnt - 1 - j)] : order[b * SS + j];
    const unsigned short* src =
        hbuf + (((size_t)half * 1025 + (tsel + 1)) * BB + b) * HH + e2;
    const unsigned int u = *(const unsigned int*)src;
    val[0] = b2f((unsigned short)u);
    val[1] = b2f((unsigned short)(u >> 16));
  }
  *(float2v*)(out + (size_t)bj * 512 + tid * 2) = val;
}

// ---------------- host ----------------
extern "C" void kernel_launch(void* const* d_in, const int* in_sizes, int n_in,
                              void* d_out, int out_size, void* d_ws, size_t ws_size,
                              hipStream_t stream) {
  (void)in_sizes; (void)n_in; (void)out_size; (void)ws_size;
  const int* inputs = (const int*)d_in[0];
  const int* seqlen = (const int*)d_in[1];
  const int* fmask  = (const int*)d_in[2];
  // d_in[3] = bmask (unused by reference), d_in[4] = out_seq_length (== S)
  const float* emb  = (const float*)d_in[5];
  const float* fWih = (const float*)d_in[6];
  const float* fWhh = (const float*)d_in[7];
  const float* fbih = (const float*)d_in[8];
  const float* fbhh = (const float*)d_in[9];
  const float* bWih = (const float*)d_in[10];
  const float* bWhh = (const float*)d_in[11];
  const float* bbih = (const float*)d_in[12];
  const float* bbhh = (const float*)d_in[13];
  float* out = (float*)d_out;

  char* ws = (char*)d_ws;
  int* ctr    = (int*)(ws + 0);                 // 2 ints
  int* counts = (int*)(ws + 256);               // 32 ints
  int* order  = (int*)(ws + 4096);              // 32*1024 ints
  const size_t o_hbuf = (size_t)1 << 18;        // 262144
  unsigned short* hbuf = (unsigned short*)(ws + o_hbuf);          // 2*1025*32*256 bf16
  const size_t o_xg = o_hbuf + (size_t)2 * 1025 * BB * HH * 2;    // 33,849,344
  unsigned short* xg = (unsigned short*)(ws + o_xg);              // 2*1024*1024*32 bf16

  // zero sync counters and the h_{-1} slots (ws is poisoned before every launch)
  hipMemsetAsync(ctr, 0, 8, stream);
  hipMemsetAsync(hbuf, 0, (size_t)BB * HH * 2, stream);
  hipMemsetAsync(hbuf + (size_t)1025 * BB * HH, 0, (size_t)BB * HH * 2, stream);

  k_scan<<<32, 256, 0, stream>>>(fmask, order, counts);
  k_gemm<<<dim3(2048, 2), 256, 0, stream>>>(inputs, seqlen, emb, fWih, bWih,
                                            fbih, bbih, fbhh, bbhh, xg);
  k_recur<<<64, 256, 0, stream>>>(fWhh, bWhh, xg, hbuf, ctr);
  k_gather<<<BB * SS, 256, 0, stream>>>(hbuf, order, counts, out);
}

// Round 3
// 5821.062 us; speedup vs baseline: 1.0601x; 1.0601x over previous
//
#include <hip/hip_runtime.h>

// ---------------- problem constants ----------------
#define VV 50000
#define EE 512
#define HH 256
#define BB 32
#define SS 1024
#define G4 1024   // 4*H

typedef __attribute__((ext_vector_type(8))) short short8;
typedef __attribute__((ext_vector_type(4))) float float4v;
typedef __attribute__((ext_vector_type(2))) float float2v;
typedef __attribute__((ext_vector_type(4))) unsigned short ushort4v;

#define MFMA(a, b, c) __builtin_amdgcn_mfma_f32_16x16x32_bf16(a, b, c, 0, 0, 0)

__device__ __forceinline__ float b2f(unsigned short u) {
  union { unsigned int i; float f; } v; v.i = ((unsigned int)u) << 16; return v.f;
}
__device__ __forceinline__ unsigned short f2b(float f) {
  union { float f; unsigned int i; } v; v.f = f;
  unsigned int u = v.i;
  return (unsigned short)((u + 0x7fffu + ((u >> 16) & 1u)) >> 16);
}
// pack 8 consecutive fp32 (16B-aligned) -> short8 of bf16
__device__ __forceinline__ short8 pack8(const float* p) {
  float4v x0 = *(const float4v*)p;
  float4v x1 = *(const float4v*)(p + 4);
  short8 r;
  r[0] = (short)f2b(x0[0]); r[1] = (short)f2b(x0[1]);
  r[2] = (short)f2b(x0[2]); r[3] = (short)f2b(x0[3]);
  r[4] = (short)f2b(x1[0]); r[5] = (short)f2b(x1[1]);
  r[6] = (short)f2b(x1[2]); r[7] = (short)f2b(x1[3]);
  return r;
}
__device__ __forceinline__ float sigm(float x) {
  return __builtin_amdgcn_rcpf(1.0f + __expf(-x));
}
__device__ __forceinline__ float tanh_f(float x) {
  return 1.0f - 2.0f * __builtin_amdgcn_rcpf(__expf(2.0f * x) + 1.0f);
}

// ---------------- kernel 1: fmask scan -> order/counts ----------------
__global__ __launch_bounds__(256) void k_scan(const int* __restrict__ fmask,
                                              int* __restrict__ order,
                                              int* __restrict__ counts) {
  __shared__ int sh[256];
  const int b = blockIdx.x;
  const int tid = threadIdx.x;
  int m0[4];
  const int base = b * SS + tid * 4;
#pragma unroll
  for (int j = 0; j < 4; ++j) m0[j] = fmask[base + j];
  const int s = m0[0] + m0[1] + m0[2] + m0[3];
  sh[tid] = s;
  __syncthreads();
  for (int off = 1; off < 256; off <<= 1) {
    int v = 0;
    if (tid >= off) v = sh[tid - off];
    __syncthreads();
    sh[tid] += v;
    __syncthreads();
  }
  const int incl = sh[tid];
  int pos = incl - s;
#pragma unroll
  for (int j = 0; j < 4; ++j) {
    if (m0[j]) order[b * SS + pos++] = tid * 4 + j;
  }
  if (tid == 255) counts[b] = incl;
}

// ---------------- kernel 2: embedding-gather + input GEMM ----------------
// xg[d][t][g][b] (bf16) = sum_k emb[tok(d,b,t)][k] * Wih_d[g][k] + bih_d[g] + bhh_d[g]
#define BM 128
#define BN 128
#define BK 32
#define LSTR 56

__global__ __launch_bounds__(256, 2) void k_gemm(
    const int* __restrict__ inputs, const int* __restrict__ seqlen,
    const float* __restrict__ emb,
    const float* __restrict__ Wih_f, const float* __restrict__ Wih_b,
    const float* __restrict__ bih_f, const float* __restrict__ bih_b,
    const float* __restrict__ bhh_f, const float* __restrict__ bhh_b,
    unsigned short* __restrict__ xg) {
  __shared__ short As[BM * LSTR];
  __shared__ short Bs[BN * LSTR];
  __shared__ int tokL[BM];

  const int d = blockIdx.y;
  const int mt = blockIdx.x >> 3, nt = blockIdx.x & 7;
  const int Mbase = mt * BM, Nbase = nt * BN;
  const int tid = threadIdx.x;
  const float* Wih = d ? Wih_b : Wih_f;

  if (tid < BM) {
    const int m = Mbase + tid;
    const int t = m >> 5, b = m & 31;
    int tok;
    if (d == 0) {
      tok = inputs[b * SS + t];
    } else {
      const int L = seqlen[b];
      tok = (t < L) ? inputs[b * SS + (L - 1 - t)] : 0;
    }
    tokL[tid] = tok;
  }
  __syncthreads();

  const int wave = tid >> 6, lane = tid & 63, ln = lane & 15, q = lane >> 4;
  const int wm = wave & 1, wn = wave >> 1;

  float4v acc[4][4];
#pragma unroll
  for (int mi = 0; mi < 4; ++mi)
#pragma unroll
    for (int ni = 0; ni < 4; ++ni) acc[mi][ni] = (float4v){0.f, 0.f, 0.f, 0.f};

  for (int kb = 0; kb < (EE / BK); ++kb) {
    const int k0 = kb * BK;
    if (kb) __syncthreads();
#pragma unroll
    for (int i = 0; i < 2; ++i) {
      const int c = tid + i * 256;
      const int row = c >> 2, sub = c & 3;
      const short8 av = pack8(emb + (size_t)tokL[row] * EE + k0 + sub * 8);
      *(short8*)(As + row * LSTR + sub * 8) = av;
      const short8 bv = pack8(Wih + (size_t)(Nbase + row) * EE + k0 + sub * 8);
      *(short8*)(Bs + row * LSTR + sub * 8) = bv;
    }
    __syncthreads();
    short8 af[4], bfr[4];
#pragma unroll
    for (int mi = 0; mi < 4; ++mi)
      af[mi] = *(const short8*)(As + (wm * 64 + mi * 16 + ln) * LSTR + q * 8);
#pragma unroll
    for (int ni = 0; ni < 4; ++ni)
      bfr[ni] = *(const short8*)(Bs + (wn * 64 + ni * 16 + ln) * LSTR + q * 8);
#pragma unroll
    for (int mi = 0; mi < 4; ++mi)
#pragma unroll
      for (int ni = 0; ni < 4; ++ni)
        acc[mi][ni] = MFMA(af[mi], bfr[ni], acc[mi][ni]);
  }

  const float* bih = d ? bih_b : bih_f;
  const float* bhh = d ? bhh_b : bhh_f;
  float biasv[4];
#pragma unroll
  for (int ni = 0; ni < 4; ++ni) {
    const int col = Nbase + wn * 64 + ni * 16 + ln;
    biasv[ni] = bih[col] + bhh[col];
  }
#pragma unroll
  for (int mi = 0; mi < 4; ++mi) {
    const int mrow = Mbase + wm * 64 + mi * 16 + q * 4;
    const int t = mrow >> 5, b0 = mrow & 31;
#pragma unroll
    for (int ni = 0; ni < 4; ++ni) {
      const int gcol = Nbase + wn * 64 + ni * 16 + ln;
      ushort4v pk;
#pragma unroll
      for (int r = 0; r < 4; ++r) pk[r] = f2b(acc[mi][ni][r] + biasv[ni]);
      *(ushort4v*)(xg + (((size_t)d * SS + t) * G4 + gcol) * BB + b0) = pk;
    }
  }
}

// ---------------- kernel 3: recurrence ----------------
// 16 active wgs: (dir d) x (unit-slice k in [0,8)). W_hh slice in VGPRs.
// Per-wg flag fl[k]=t+1 published after step t; readers poll all 8 flags of
// their direction with one batched cacheline read (4 x i64 relaxed atomic
// loads) + acquire fence. xg is software-pipelined one step ahead.
__global__ __launch_bounds__(256, 1) void k_recur(
    const float* __restrict__ Whh_f, const float* __restrict__ Whh_b,
    const unsigned short* __restrict__ xg, unsigned short* __restrict__ hbuf,
    int* __restrict__ flags) {
  const int beta = blockIdx.x;
  const int xcd = beta & 7, slot = beta >> 3;   // blockIdx%8 ~ XCD (perf heuristic only)
  if (xcd >= 2) return;
  const int d = xcd, k = slot;
  const float* Whh = d ? Whh_b : Whh_f;
  const int tid = threadIdx.x;
  const int wave = tid >> 6, lane = tid & 63, ln = lane & 15, q = lane >> 4;
  const int g = wave & 1, nw = wave >> 1;
  const int chain = nw * 16 + ln;               // this lane's batch chain (C col)
  const int ubase = k * 32 + g * 16 + q * 4;    // first of this lane's 4 units (C rows)

  // loop-invariant weight fragments: A[m][kk], m=ln, kk=q*8+j
  short8 w[4][8];
#pragma unroll
  for (int G = 0; G < 4; ++G) {
    const int grow = G * 256 + k * 32 + g * 16 + ln;
#pragma unroll
    for (int kt = 0; kt < 8; ++kt)
      w[G][kt] = pack8(Whh + (size_t)grow * HH + kt * 32 + q * 8);
  }

  float c4[4] = {0.f, 0.f, 0.f, 0.f};
  unsigned short* hb = hbuf + (size_t)d * 1025 * BB * HH;
  const unsigned short* xgd = xg + (size_t)d * SS * G4 * BB;
  int* fl = flags + d * 2048;                   // 8 ints, one cacheline; dirs 8KB apart
  const unsigned long long* f64 = (const unsigned long long*)fl;

  // prefetch xg for t=0
  unsigned short xc[16], xn[16];
#pragma unroll
  for (int G = 0; G < 4; ++G)
#pragma unroll
    for (int r = 0; r < 4; ++r)
      xc[G * 4 + r] = xgd[((size_t)0 * G4 + (G * 256 + ubase + r)) * BB + chain];

  for (int t = 0; t < SS; ++t) {
    if (t > 0) {
      while (true) {
        unsigned long long v[4];
#pragma unroll
        for (int i = 0; i < 4; ++i)
          v[i] = __hip_atomic_load(f64 + i, __ATOMIC_RELAXED, __HIP_MEMORY_SCOPE_AGENT);
        bool ok = true;
#pragma unroll
        for (int i = 0; i < 4; ++i) {
          const int lo = (int)(unsigned int)v[i];
          const int hi = (int)(v[i] >> 32);
          ok = ok && ((2 * i == k) || (lo >= t)) && ((2 * i + 1 == k) || (hi >= t));
        }
        if (ok) break;
        __builtin_amdgcn_s_sleep(1);
      }
      __builtin_amdgcn_fence(__ATOMIC_ACQUIRE, "agent");
    }

    // B fragments: h_{t-1}[chain][k] rows, contiguous 16B
    const unsigned short* hrow = hb + ((size_t)t * BB + chain) * HH;
    short8 hf[8];
#pragma unroll
    for (int kt = 0; kt < 8; ++kt)
      hf[kt] = *(const short8*)(hrow + kt * 32 + q * 8);

    // issue next step's xg prefetch AFTER hf loads (hf's waitcnt stays cheap),
    // consumed one full step later -> HBM latency off the critical path
    if (t + 1 < SS) {
#pragma unroll
      for (int G = 0; G < 4; ++G)
#pragma unroll
        for (int r = 0; r < 4; ++r)
          xn[G * 4 + r] = xgd[((size_t)(t + 1) * G4 + (G * 256 + ubase + r)) * BB + chain];
    }

    float4v acc[4];
#pragma unroll
    for (int G = 0; G < 4; ++G) acc[G] = (float4v){0.f, 0.f, 0.f, 0.f};
#pragma unroll
    for (int kt = 0; kt < 8; ++kt)
#pragma unroll
      for (int G = 0; G < 4; ++G)
        acc[G] = MFMA(w[G][kt], hf[kt], acc[G]);

    unsigned long long pv = 0ull;
#pragma unroll
    for (int r = 0; r < 4; ++r) {
      const float gi = acc[0][r] + b2f(xc[0 * 4 + r]);
      const float gf = acc[1][r] + b2f(xc[1 * 4 + r]);
      const float gg = acc[2][r] + b2f(xc[2 * 4 + r]);
      const float go = acc[3][r] + b2f(xc[3 * 4 + r]);
      const float cn = sigm(gf) * c4[r] + sigm(gi) * tanh_f(gg);
      c4[r] = cn;
      const float h = sigm(go) * tanh_f(cn);
      pv |= ((unsigned long long)f2b(h)) << (16 * r);
    }
    __hip_atomic_store((unsigned long long*)(hb + ((size_t)(t + 1) * BB + chain) * HH + ubase),
                       pv, __ATOMIC_RELAXED, __HIP_MEMORY_SCOPE_AGENT);
    __syncthreads();   // drains vmcnt: all 4 waves' h stores are in L2 after this
    if (tid == 0)
      __hip_atomic_store(fl + k, t + 1, __ATOMIC_RELEASE, __HIP_MEMORY_SCOPE_AGENT);

#pragma unroll
    for (int i = 0; i < 16; ++i) xc[i] = xn[i];
  }
}

// ---------------- kernel 4: masked compaction gather -> out (fp32) ----------------
__global__ __launch_bounds__(256) void k_gather(
    const unsigned short* __restrict__ hbuf, const int* __restrict__ order,
    const int* __restrict__ counts, float* __restrict__ out) {
  const int bj = blockIdx.x;            // (b, j)
  const int b = bj >> 10, j = bj & 1023;
  const int tid = threadIdx.x;
  const int cnt = counts[b];
  float2v val = (float2v){0.f, 0.f};
  if (j < cnt) {
    const int half = tid >> 7;          // 0: forward, 1: backward
    const int e2 = (tid & 127) * 2;
    const int tsel = half ? order[b * SS + (cnt - 1 - j)] : order[b * SS + j];
    const unsigned short* src =
        hbuf + (((size_t)half * 1025 + (tsel + 1)) * BB + b) * HH + e2;
    const unsigned int u = *(const unsigned int*)src;
    val[0] = b2f((unsigned short)u);
    val[1] = b2f((unsigned short)(u >> 16));
  }
  *(float2v*)(out + (size_t)bj * 512 + tid * 2) = val;
}

// ---------------- host ----------------
extern "C" void kernel_launch(void* const* d_in, const int* in_sizes, int n_in,
                              void* d_out, int out_size, void* d_ws, size_t ws_size,
                              hipStream_t stream) {
  (void)in_sizes; (void)n_in; (void)out_size; (void)ws_size;
  const int* inputs = (const int*)d_in[0];
  const int* seqlen = (const int*)d_in[1];
  const int* fmask  = (const int*)d_in[2];
  const float* emb  = (const float*)d_in[5];
  const float* fWih = (const float*)d_in[6];
  const float* fWhh = (const float*)d_in[7];
  const float* fbih = (const float*)d_in[8];
  const float* fbhh = (const float*)d_in[9];
  const float* bWih = (const float*)d_in[10];
  const float* bWhh = (const float*)d_in[11];
  const float* bbih = (const float*)d_in[12];
  const float* bbhh = (const float*)d_in[13];
  float* out = (float*)d_out;

  char* ws = (char*)d_ws;
  int* flags  = (int*)(ws + 0);                 // fl[d] at ws + d*8192, 8 ints each
  int* counts = (int*)(ws + 1024);              // 32 ints (own line, shared page ok)
  int* order  = (int*)(ws + 16384);             // 32*1024 ints
  const size_t o_hbuf = (size_t)1 << 18;
  unsigned short* hbuf = (unsigned short*)(ws + o_hbuf);          // 2*1025*32*256 bf16
  const size_t o_xg = o_hbuf + (size_t)2 * 1025 * BB * HH * 2;
  unsigned short* xg = (unsigned short*)(ws + o_xg);              // 2*1024*1024*32 bf16

  hipMemsetAsync(flags, 0, 32, stream);
  hipMemsetAsync((char*)flags + 8192, 0, 32, stream);
  hipMemsetAsync(hbuf, 0, (size_t)BB * HH * 2, stream);
  hipMemsetAsync(hbuf + (size_t)1025 * BB * HH, 0, (size_t)BB * HH * 2, stream);

  k_scan<<<32, 256, 0, stream>>>(fmask, order, counts);
  k_gemm<<<dim3(2048, 2), 256, 0, stream>>>(inputs, seqlen, emb, fWih, bWih,
                                            fbih, bbih, fbhh, bbhh, xg);
  k_recur<<<64, 256, 0, stream>>>(fWhh, bWhh, xg, hbuf, (int*)flags);
  k_gather<<<BB * SS, 256, 0, stream>>>(hbuf, order, counts, out);
}